// Round 1
// baseline (308.715 us; speedup 1.0000x reference)
//
#include <hip/hip_runtime.h>
#include <hip/hip_bf16.h>
#include <stdint.h>

// ALBEF contrastive loss: B=256, Q=32, L=40, VW=TW=768, D=256.
// S[b,c] = sim_i2t(b,c)/temp ; sim_t2i = S^T (algebraic identity), so the
// loss only needs row- and column-logsumexp of one 256x256 matrix.

using f32x4  = __attribute__((ext_vector_type(4))) float;
using bf16x8 = __attribute__((ext_vector_type(8))) short;

__device__ __forceinline__ short f2bf(float f) {
  union { float f; uint32_t u; } x; x.f = f;
  uint32_t r = x.u + 0x7FFFu + ((x.u >> 16) & 1u);  // RNE
  return (short)(r >> 16);
}

__device__ __forceinline__ bf16x8 pack8(float4 v0, float4 v1) {
  bf16x8 r;
  r[0] = f2bf(v0.x); r[1] = f2bf(v0.y); r[2] = f2bf(v0.z); r[3] = f2bf(v0.w);
  r[4] = f2bf(v1.x); r[5] = f2bf(v1.y); r[6] = f2bf(v1.z); r[7] = f2bf(v1.w);
  return r;
}

// ---------------- mask preprocess: zero [CLS]=pos0 and [SEP]=last nonzero ---
__global__ void k_mask(const int* __restrict__ tm,
                       unsigned long long* __restrict__ mb,
                       float* __restrict__ nw) {
  int b = blockIdx.x * blockDim.x + threadIdx.x;
  if (b >= 256) return;
  unsigned long long bits = 0ull;
  int sep = -1;
  #pragma unroll
  for (int t = 1; t < 40; ++t) {
    if (tm[b * 40 + t] > 0) { bits |= (1ull << t); sep = t; }
  }
  if (sep >= 0) bits &= ~(1ull << sep);
  mb[b] = bits;
  nw[b] = (float)__popcll(bits);
}

// ---------------- W transpose (f32): Wt[d][k] = W[k][d] --------------------
__global__ void k_tr(const float* __restrict__ Wc, const float* __restrict__ Ww,
                     float* __restrict__ Wct, float* __restrict__ Wwt) {
  int i = blockIdx.x * 256 + threadIdx.x;
  const int N = 768 * 256;
  if (i < N) {
    int k = i >> 8, d = i & 255;
    Wct[d * 768 + k] = Wc[i];
  } else {
    int j = i - N;
    int k = j >> 8, d = j & 255;
    Wwt[d * 768 + k] = Ww[j];
  }
}

// ---------------- projection GEMM: P[M,256] = X[M,768] @ W  (bf16 MFMA) ----
__global__ __launch_bounds__(256) void k_proj(const float* __restrict__ X,
                                              const float* __restrict__ Wt,
                                              float* __restrict__ P) {
  const int m0 = blockIdx.x * 32;
  const int w = threadIdx.x >> 6, l = threadIdx.x & 63;
  const int lr = l & 15, lg = l >> 4;
  const int n0 = w * 64;

  f32x4 acc[2][4];
  #pragma unroll
  for (int mi = 0; mi < 2; ++mi)
    #pragma unroll
    for (int ni = 0; ni < 4; ++ni) acc[mi][ni] = f32x4{0.f, 0.f, 0.f, 0.f};

  const float* arow0 = X + (size_t)(m0 + lr) * 768 + lg * 8;
  const float* arow1 = arow0 + (size_t)16 * 768;
  const float* brow[4];
  #pragma unroll
  for (int ni = 0; ni < 4; ++ni)
    brow[ni] = Wt + (size_t)(n0 + ni * 16 + lr) * 768 + lg * 8;

  #pragma unroll 4
  for (int ks = 0; ks < 24; ++ks) {
    const int k0 = ks * 32;
    bf16x8 a[2], bb[4];
    a[0] = pack8(*(const float4*)(arow0 + k0), *(const float4*)(arow0 + k0 + 4));
    a[1] = pack8(*(const float4*)(arow1 + k0), *(const float4*)(arow1 + k0 + 4));
    #pragma unroll
    for (int ni = 0; ni < 4; ++ni)
      bb[ni] = pack8(*(const float4*)(brow[ni] + k0), *(const float4*)(brow[ni] + k0 + 4));
    #pragma unroll
    for (int mi = 0; mi < 2; ++mi)
      #pragma unroll
      for (int ni = 0; ni < 4; ++ni)
        acc[mi][ni] = __builtin_amdgcn_mfma_f32_16x16x32_bf16(a[mi], bb[ni], acc[mi][ni], 0, 0, 0);
  }

  #pragma unroll
  for (int mi = 0; mi < 2; ++mi)
    #pragma unroll
    for (int ni = 0; ni < 4; ++ni)
      #pragma unroll
      for (int j = 0; j < 4; ++j) {
        int row = m0 + mi * 16 + lg * 4 + j;
        int col = n0 + ni * 16 + lr;
        P[(size_t)row * 256 + col] = acc[mi][ni][j];
      }
}

// ---------------- bias + l2 normalize + bf16 store (linear layout) ---------
__global__ __launch_bounds__(256) void k_norm(const float* __restrict__ P,
                                              const float* __restrict__ bias,
                                              unsigned short* __restrict__ out) {
  const int w = threadIdx.x >> 6, l = threadIdx.x & 63;
  const int r = blockIdx.x * 4 + w;
  float4 v = *(const float4*)(P + (size_t)r * 256 + l * 4);
  float4 bb = *(const float4*)(bias + l * 4);
  v.x += bb.x; v.y += bb.y; v.z += bb.z; v.w += bb.w;
  float ss = v.x * v.x + v.y * v.y + v.z * v.z + v.w * v.w;
  #pragma unroll
  for (int m = 1; m < 64; m <<= 1) ss += __shfl_xor(ss, m);
  const float sc = rsqrtf(ss);
  ushort4 o;
  o.x = (unsigned short)f2bf(v.x * sc);
  o.y = (unsigned short)f2bf(v.y * sc);
  o.z = (unsigned short)f2bf(v.z * sc);
  o.w = (unsigned short)f2bf(v.w * sc);
  *(ushort4*)(out + (size_t)r * 256 + l * 4) = o;
}

// ---------------- pairwise sim: S[b,c] for 4b x 4c per block ---------------
__global__ __launch_bounds__(256) void k_pair(const unsigned short* __restrict__ CF,
                                              const unsigned short* __restrict__ WF,
                                              const unsigned long long* __restrict__ MB,
                                              const float* __restrict__ NW,
                                              const float* __restrict__ TEMP,
                                              float* __restrict__ S) {
  extern __shared__ char smem[];
  unsigned short* cfs = (unsigned short*)smem;             // 65536 B, [4][32][256] swz
  unsigned short* wfs = (unsigned short*)(smem + 65536);   // 81920 B, [4][40][256] swz
  const int tid = threadIdx.x;
  const int b0 = blockIdx.x * 4, c0 = blockIdx.y * 4;

  #pragma unroll
  for (int it = 0; it < 16; ++it) {
    int chunk = it * 256 + tid;        // 0..4095 chunks of 16B
    int bi = chunk >> 10;
    int within = chunk & 1023;
    int row = within >> 5;
    int slot = within & 31;
    uint4 v = *(const uint4*)(CF + ((size_t)(b0 + bi) * 32 + row) * 256 + slot * 8);
    *(uint4*)(cfs + bi * 8192 + row * 256 + ((slot ^ (row & 7)) * 8)) = v;
  }
  #pragma unroll
  for (int ci = 0; ci < 4; ++ci) {
    #pragma unroll
    for (int it = 0; it < 5; ++it) {
      int chunk = it * 256 + tid;      // 0..1279
      int row = chunk >> 5;
      int slot = chunk & 31;
      uint4 v = *(const uint4*)(WF + ((size_t)(c0 + ci) * 40 + row) * 256 + slot * 8);
      *(uint4*)(wfs + ci * 10240 + row * 256 + ((slot ^ (row & 7)) * 8)) = v;
    }
  }
  __syncthreads();

  const int w = tid >> 6, l = tid & 63;
  const int lr = l & 15, lg = l >> 4;
  const int b = b0 + w;
  const float invt = 1.0f / TEMP[0];

  bf16x8 a[2][8];
  #pragma unroll
  for (int mi = 0; mi < 2; ++mi)
    #pragma unroll
    for (int ks = 0; ks < 8; ++ks) {
      int r = mi * 16 + lr;
      int slot = ks * 4 + lg;
      a[mi][ks] = *(const bf16x8*)(cfs + w * 8192 + r * 256 + ((slot ^ (r & 7)) * 8));
    }

  #pragma unroll 1
  for (int ci = 0; ci < 4; ++ci) {
    const int cg = c0 + ci;
    f32x4 acc[2][3];
    #pragma unroll
    for (int mi = 0; mi < 2; ++mi)
      #pragma unroll
      for (int ni = 0; ni < 3; ++ni) acc[mi][ni] = f32x4{0.f, 0.f, 0.f, 0.f};

    #pragma unroll
    for (int ks = 0; ks < 8; ++ks) {
      bf16x8 bf[3];
      #pragma unroll
      for (int ni = 0; ni < 3; ++ni) {
        int t = ni * 16 + lr;
        if (t > 39) t = 39;
        int slot = ks * 4 + lg;
        bf[ni] = *(const bf16x8*)(wfs + ci * 10240 + t * 256 + ((slot ^ (t & 7)) * 8));
      }
      #pragma unroll
      for (int mi = 0; mi < 2; ++mi)
        #pragma unroll
        for (int ni = 0; ni < 3; ++ni)
          acc[mi][ni] = __builtin_amdgcn_mfma_f32_16x16x32_bf16(a[mi][ks], bf[ni], acc[mi][ni], 0, 0, 0);
    }

    const unsigned long long vb = MB[cg];
    const float nw = NW[cg];
    bool val[3];
    #pragma unroll
    for (int ni = 0; ni < 3; ++ni) {
      int t = ni * 16 + lr;
      val[ni] = (t < 40) && ((vb >> t) & 1ull);
      if (!val[ni]) {
        #pragma unroll
        for (int mi = 0; mi < 2; ++mi)
          #pragma unroll
          for (int j = 0; j < 4; ++j) acc[mi][ni][j] = -2.0f;
      }
    }

    float rp[2][4];
    #pragma unroll
    for (int mi = 0; mi < 2; ++mi)
      #pragma unroll
      for (int j = 0; j < 4; ++j)
        rp[mi][j] = fmaxf(fmaxf(acc[mi][0][j], acc[mi][1][j]), acc[mi][2][j]);
    #pragma unroll
    for (int m = 1; m < 16; m <<= 1) {
      #pragma unroll
      for (int mi = 0; mi < 2; ++mi)
        #pragma unroll
        for (int j = 0; j < 4; ++j)
          rp[mi][j] = fmaxf(rp[mi][j], __shfl_xor(rp[mi][j], m));
    }
    float rsum = rp[0][0] + rp[0][1] + rp[0][2] + rp[0][3]
               + rp[1][0] + rp[1][1] + rp[1][2] + rp[1][3];
    rsum += __shfl_xor(rsum, 16);
    rsum += __shfl_xor(rsum, 32);

    float cp[3];
    #pragma unroll
    for (int ni = 0; ni < 3; ++ni) {
      cp[ni] = fmaxf(fmaxf(fmaxf(acc[0][ni][0], acc[0][ni][1]),
                           fmaxf(acc[0][ni][2], acc[0][ni][3])),
                     fmaxf(fmaxf(acc[1][ni][0], acc[1][ni][1]),
                           fmaxf(acc[1][ni][2], acc[1][ni][3])));
      cp[ni] = fmaxf(cp[ni], __shfl_xor(cp[ni], 16));
      cp[ni] = fmaxf(cp[ni], __shfl_xor(cp[ni], 32));
    }
    float csum = (val[0] ? cp[0] : 0.f) + (val[1] ? cp[1] : 0.f) + (val[2] ? cp[2] : 0.f);
    #pragma unroll
    for (int m = 1; m < 64; m <<= 1) csum += __shfl_xor(csum, m);
    csum *= 0.25f;

    float s = (rsum * 0.03125f + csum / nw) * invt;
    if (l == 0) S[(size_t)b * 256 + cg] = s;
  }
}

// ---------------- loss: row-LSE + col-LSE of S ------------------------------
__global__ __launch_bounds__(256) void k_loss(const float* __restrict__ S,
                                              float* __restrict__ out) {
  __shared__ float red[256];
  const int b = threadIdx.x;
  float m1 = -1e30f, m2 = -1e30f;
  for (int j = 0; j < 256; ++j) {
    m1 = fmaxf(m1, S[b * 256 + j]);
    m2 = fmaxf(m2, S[j * 256 + b]);
  }
  float s1 = 0.f, s2 = 0.f;
  for (int j = 0; j < 256; ++j) {
    s1 += expf(S[b * 256 + j] - m1);
    s2 += expf(S[j * 256 + b] - m2);
  }
  float v = (m1 + logf(s1)) + (m2 + logf(s2)) - 2.0f * S[b * 256 + b];
  red[b] = v;
  __syncthreads();
  for (int st = 128; st > 0; st >>= 1) {
    if (b < st) red[b] += red[b + st];
    __syncthreads();
  }
  if (b == 0) out[0] = red[0] * (1.0f / 512.0f);
}

extern "C" void kernel_launch(void* const* d_in, const int* in_sizes, int n_in,
                              void* d_out, int out_size, void* d_ws, size_t ws_size,
                              hipStream_t stream) {
  const float* concept = (const float*)d_in[0];
  const float* text    = (const float*)d_in[1];
  const int*   tmask   = (const int*)d_in[2];
  const float* Wc      = (const float*)d_in[3];
  const float* bc      = (const float*)d_in[4];
  const float* Ww      = (const float*)d_in[5];
  const float* bw      = (const float*)d_in[6];
  const float* temp    = (const float*)d_in[7];
  float* out = (float*)d_out;
  char* ws = (char*)d_ws;

  float*              Sm  = (float*)(ws + 0);
  float*              Wct = (float*)(ws + 262144);
  float*              Wwt = (float*)(ws + 1048576);
  float*              Pcf = (float*)(ws + 1835008);
  float*              Pwf = (float*)(ws + 10223616);
  unsigned short*     CFb = (unsigned short*)(ws + 20709376);
  unsigned short*     WFb = (unsigned short*)(ws + 24903680);
  unsigned long long* MBp = (unsigned long long*)(ws + 30146560);
  float*              NWp = (float*)(ws + 30148608);

  hipFuncSetAttribute((const void*)k_pair,
                      hipFuncAttributeMaxDynamicSharedMemorySize, 147456);

  k_mask<<<1, 256, 0, stream>>>(tmask, MBp, NWp);
  k_tr<<<1536, 256, 0, stream>>>(Wc, Ww, Wct, Wwt);
  k_proj<<<256, 256, 0, stream>>>(concept, Wct, Pcf);
  k_proj<<<320, 256, 0, stream>>>(text, Wwt, Pwf);
  k_norm<<<2048, 256, 0, stream>>>(Pcf, bc, CFb);
  k_norm<<<2560, 256, 0, stream>>>(Pwf, bw, WFb);
  dim3 pg(64, 64);
  k_pair<<<pg, 256, 147456, stream>>>(CFb, WFb, MBp, NWp, temp, Sm);
  k_loss<<<1, 256, 0, stream>>>(Sm, out);
}

// Round 2
// 219.298 us; speedup vs baseline: 1.4077x; 1.4077x over previous
//
#include <hip/hip_runtime.h>
#include <hip/hip_bf16.h>
#include <stdint.h>

// ALBEF contrastive loss: B=256, Q=32, L=40, VW=TW=768, D=256.
// S = sim_i2t/temp; sim_t2i = S^T, so loss = row-LSE + col-LSE of one S.

using f32x4  = __attribute__((ext_vector_type(4))) float;
using bf16x8 = __attribute__((ext_vector_type(8))) short;

__device__ __forceinline__ short f2bf(float f) {
  union { float f; uint32_t u; } x; x.f = f;
  uint32_t r = x.u + 0x7FFFu + ((x.u >> 16) & 1u);  // RNE
  return (short)(r >> 16);
}

__device__ __forceinline__ bf16x8 pack8(float4 v0, float4 v1) {
  bf16x8 r;
  r[0] = f2bf(v0.x); r[1] = f2bf(v0.y); r[2] = f2bf(v0.z); r[3] = f2bf(v0.w);
  r[4] = f2bf(v1.x); r[5] = f2bf(v1.y); r[6] = f2bf(v1.z); r[7] = f2bf(v1.w);
  return r;
}

// async global->LDS, 16B per lane; LDS dest = wave-uniform base + lane*16
__device__ __forceinline__ void gl_lds16(const unsigned short* g, unsigned short* l) {
  __builtin_amdgcn_global_load_lds(
      (const __attribute__((address_space(1))) void*)g,
      (__attribute__((address_space(3))) void*)l, 16, 0, 0);
}

// ---------------- mask preprocess: zero [CLS]=pos0 and [SEP]=last nonzero ---
__global__ void k_mask(const int* __restrict__ tm,
                       unsigned long long* __restrict__ mb,
                       float* __restrict__ nw) {
  int b = blockIdx.x * blockDim.x + threadIdx.x;
  if (b >= 256) return;
  unsigned long long bits = 0ull;
  int sep = -1;
  #pragma unroll
  for (int t = 1; t < 40; ++t) {
    if (tm[b * 40 + t] > 0) { bits |= (1ull << t); sep = t; }
  }
  if (sep >= 0) bits &= ~(1ull << sep);
  mb[b] = bits;
  nw[b] = (float)__popcll(bits);
}

// ---------------- X f32 -> bf16 (concept then text, concatenated) ----------
__global__ __launch_bounds__(256) void k_cvt(const float* __restrict__ A,
                                             const float* __restrict__ B,
                                             unsigned short* __restrict__ Ab,
                                             unsigned short* __restrict__ Bb) {
  size_t i = ((size_t)blockIdx.x * 256 + threadIdx.x) * 8;
  const size_t nA = 6291456;  // 8192*768
  const float* s; unsigned short* d; size_t off;
  if (i < nA) { s = A; d = Ab; off = i; }
  else        { s = B; d = Bb; off = i - nA; }
  float4 v0 = *(const float4*)(s + off);
  float4 v1 = *(const float4*)(s + off + 4);
  *(bf16x8*)(d + off) = pack8(v0, v1);
}

// ---------------- W transpose + cvt: Wt_bf16[d][k] = W[k][d] ---------------
__global__ __launch_bounds__(256) void k_trw(const float* __restrict__ Wc,
                                             const float* __restrict__ Ww,
                                             unsigned short* __restrict__ Wct,
                                             unsigned short* __restrict__ Wwt) {
  int i = blockIdx.x * 256 + threadIdx.x;   // 0 .. 2*196608-1
  const int N = 196608;
  const float* W = (i < N) ? Wc : Ww;
  unsigned short* O = (i < N) ? Wct : Wwt;
  int j = (i < N) ? i : i - N;
  int dd = j / 768, k = j - dd * 768;
  O[j] = (unsigned short)f2bf(W[k * 256 + dd]);
}

// ---------------- proj GEMM + fused bias + l2norm -> bf16 ------------------
// P[M,256] = X[M,768] @ W; per block: 32 rows, 4 waves x 64 cols.
__global__ __launch_bounds__(256) void k_proj(const unsigned short* __restrict__ Xb,
                                              const unsigned short* __restrict__ Wtb,
                                              const float* __restrict__ bias,
                                              unsigned short* __restrict__ out) {
  __shared__ float red[32][4];
  const int m0 = blockIdx.x * 32;
  const int w = threadIdx.x >> 6, l = threadIdx.x & 63;
  const int lr = l & 15, lg = l >> 4;
  const int n0 = w * 64;

  f32x4 acc[2][4];
  #pragma unroll
  for (int mi = 0; mi < 2; ++mi)
    #pragma unroll
    for (int ni = 0; ni < 4; ++ni) acc[mi][ni] = f32x4{0.f, 0.f, 0.f, 0.f};

  #pragma unroll 2
  for (int ks = 0; ks < 24; ++ks) {
    bf16x8 a0 = *(const bf16x8*)(Xb + (size_t)(m0 + lr) * 768 + ks * 32 + lg * 8);
    bf16x8 a1 = *(const bf16x8*)(Xb + (size_t)(m0 + 16 + lr) * 768 + ks * 32 + lg * 8);
    bf16x8 bb[4];
    #pragma unroll
    for (int ni = 0; ni < 4; ++ni)
      bb[ni] = *(const bf16x8*)(Wtb + (size_t)(n0 + ni * 16 + lr) * 768 + ks * 32 + lg * 8);
    #pragma unroll
    for (int ni = 0; ni < 4; ++ni)
      acc[0][ni] = __builtin_amdgcn_mfma_f32_16x16x32_bf16(a0, bb[ni], acc[0][ni], 0, 0, 0);
    #pragma unroll
    for (int ni = 0; ni < 4; ++ni)
      acc[1][ni] = __builtin_amdgcn_mfma_f32_16x16x32_bf16(a1, bb[ni], acc[1][ni], 0, 0, 0);
  }

  float bv[4];
  #pragma unroll
  for (int ni = 0; ni < 4; ++ni) bv[ni] = bias[n0 + ni * 16 + lr];

  float ss[2][4];
  #pragma unroll
  for (int mi = 0; mi < 2; ++mi)
    #pragma unroll
    for (int j = 0; j < 4; ++j) {
      float t = 0.f;
      #pragma unroll
      for (int ni = 0; ni < 4; ++ni) {
        acc[mi][ni][j] += bv[ni];
        t += acc[mi][ni][j] * acc[mi][ni][j];
      }
      ss[mi][j] = t;
    }
  #pragma unroll
  for (int m = 1; m <= 8; m <<= 1)
    #pragma unroll
    for (int mi = 0; mi < 2; ++mi)
      #pragma unroll
      for (int j = 0; j < 4; ++j)
        ss[mi][j] += __shfl_xor(ss[mi][j], m);
  if (lr == 0) {
    #pragma unroll
    for (int mi = 0; mi < 2; ++mi)
      #pragma unroll
      for (int j = 0; j < 4; ++j)
        red[mi * 16 + lg * 4 + j][w] = ss[mi][j];
  }
  __syncthreads();
  #pragma unroll
  for (int mi = 0; mi < 2; ++mi)
    #pragma unroll
    for (int j = 0; j < 4; ++j) {
      int r = mi * 16 + lg * 4 + j;
      float sc = rsqrtf(red[r][0] + red[r][1] + red[r][2] + red[r][3]);
      #pragma unroll
      for (int ni = 0; ni < 4; ++ni)
        out[(size_t)(m0 + r) * 256 + n0 + ni * 16 + lr] =
            (unsigned short)f2bf(acc[mi][ni][j] * sc);
    }
}

// ---------------- pairwise sim: 4 b x 16 c per block, dbuf LDS wf ----------
// LDS per buffer: [40][256] bf16 = 20KB, physical slot = s ^ (t&7) (16B units)
__global__ __launch_bounds__(256, 3) void k_pair(const unsigned short* __restrict__ CF,
                                                 const unsigned short* __restrict__ WF,
                                                 const unsigned long long* __restrict__ MB,
                                                 const float* __restrict__ NW,
                                                 const float* __restrict__ TEMP,
                                                 float* __restrict__ S,
                                                 float* __restrict__ St) {
  __shared__ unsigned short wfs[2][10240];
  const int tid = threadIdx.x;
  const int w = tid >> 6, l = tid & 63;
  const int lr = l & 15, lg = l >> 4;
  const int b0 = blockIdx.x * 4, c0 = blockIdx.y * 16;
  const int b = b0 + w;
  const float invt = 1.0f / TEMP[0];

  // stage c0 into buf 0: 1280 16B chunks; wave w covers chunks [(w*5+j)*64 ..)
  #pragma unroll
  for (int j = 0; j < 5; ++j) {
    int idx = w * 5 + j;
    int ch = idx * 64 + l;
    int t = ch >> 5, sl = ch & 31;
    gl_lds16(WF + ((size_t)c0 * 40 + t) * 256 + ((sl ^ (t & 7)) * 8),
             &wfs[0][idx * 512]);
  }

  // hoist A frags for this wave's b (L2-resident CF)
  bf16x8 a[2][8];
  #pragma unroll
  for (int mi = 0; mi < 2; ++mi)
    #pragma unroll
    for (int ks = 0; ks < 8; ++ks)
      a[mi][ks] = *(const bf16x8*)(CF + (size_t)(b * 32 + mi * 16 + lr) * 256 + (ks * 4 + lg) * 8);

  asm volatile("s_waitcnt vmcnt(0)" ::: "memory");
  __syncthreads();

  int cur = 0;
  #pragma unroll 1
  for (int ci = 0; ci < 16; ++ci) {
    const int cg = c0 + ci;
    if (ci < 15) {  // prefetch next wf tile into the free buffer
      #pragma unroll
      for (int j = 0; j < 5; ++j) {
        int idx = w * 5 + j;
        int ch = idx * 64 + l;
        int t = ch >> 5, sl = ch & 31;
        gl_lds16(WF + ((size_t)(cg + 1) * 40 + t) * 256 + ((sl ^ (t & 7)) * 8),
                 &wfs[cur ^ 1][idx * 512]);
      }
    }

    f32x4 acc[2][3];
    #pragma unroll
    for (int mi = 0; mi < 2; ++mi)
      #pragma unroll
      for (int ni = 0; ni < 3; ++ni) acc[mi][ni] = f32x4{0.f, 0.f, 0.f, 0.f};

    #pragma unroll
    for (int ks = 0; ks < 8; ++ks) {
      bf16x8 bfv[3];
      #pragma unroll
      for (int ni = 0; ni < 3; ++ni) {
        int t = ni * 16 + lr;
        if (t > 39) t = 39;
        int s = ks * 4 + lg;
        bfv[ni] = *(const bf16x8*)(&wfs[cur][t * 256 + ((s ^ (t & 7)) * 8)]);
      }
      #pragma unroll
      for (int mi = 0; mi < 2; ++mi)
        #pragma unroll
        for (int ni = 0; ni < 3; ++ni)
          acc[mi][ni] = __builtin_amdgcn_mfma_f32_16x16x32_bf16(a[mi][ks], bfv[ni], acc[mi][ni], 0, 0, 0);
    }

    // masking: invalid t -> -2 (reference fill)
    const unsigned long long vb = MB[cg];
    const float nw = NW[cg];
    bool val[3];
    #pragma unroll
    for (int ni = 0; ni < 3; ++ni) {
      int t = ni * 16 + lr;
      val[ni] = (t < 40) && ((vb >> t) & 1ull);
      if (!val[ni]) {
        #pragma unroll
        for (int mi = 0; mi < 2; ++mi)
          #pragma unroll
          for (int j = 0; j < 4; ++j) acc[mi][ni][j] = -2.0f;
      }
    }

    // per-q max over t -> mean over 32 q
    float rp[2][4];
    #pragma unroll
    for (int mi = 0; mi < 2; ++mi)
      #pragma unroll
      for (int j = 0; j < 4; ++j)
        rp[mi][j] = fmaxf(fmaxf(acc[mi][0][j], acc[mi][1][j]), acc[mi][2][j]);
    #pragma unroll
    for (int m = 1; m < 16; m <<= 1) {
      #pragma unroll
      for (int mi = 0; mi < 2; ++mi)
        #pragma unroll
        for (int j = 0; j < 4; ++j)
          rp[mi][j] = fmaxf(rp[mi][j], __shfl_xor(rp[mi][j], m));
    }
    float rsum = rp[0][0] + rp[0][1] + rp[0][2] + rp[0][3]
               + rp[1][0] + rp[1][1] + rp[1][2] + rp[1][3];
    rsum += __shfl_xor(rsum, 16);
    rsum += __shfl_xor(rsum, 32);

    // per-t max over q (valid t only) -> mean over n_words
    float cp[3];
    #pragma unroll
    for (int ni = 0; ni < 3; ++ni) {
      cp[ni] = fmaxf(fmaxf(fmaxf(acc[0][ni][0], acc[0][ni][1]),
                           fmaxf(acc[0][ni][2], acc[0][ni][3])),
                     fmaxf(fmaxf(acc[1][ni][0], acc[1][ni][1]),
                           fmaxf(acc[1][ni][2], acc[1][ni][3])));
      cp[ni] = fmaxf(cp[ni], __shfl_xor(cp[ni], 16));
      cp[ni] = fmaxf(cp[ni], __shfl_xor(cp[ni], 32));
    }
    float csum = (val[0] ? cp[0] : 0.f) + (val[1] ? cp[1] : 0.f) + (val[2] ? cp[2] : 0.f);
    #pragma unroll
    for (int m = 1; m < 64; m <<= 1) csum += __shfl_xor(csum, m);
    csum *= 0.25f;  // col values replicated across 4 lane-groups

    float sv = (rsum * 0.03125f + csum / nw) * invt;
    if (l == 0) {
      S [(size_t)b  * 256 + cg] = sv;
      St[(size_t)cg * 256 + b ] = sv;
    }

    asm volatile("s_waitcnt vmcnt(0)" ::: "memory");
    __syncthreads();
    cur ^= 1;
  }
}

// ---------------- loss: row-LSE (via St) + col-LSE of S --------------------
__global__ __launch_bounds__(256) void k_loss(const float* __restrict__ S,
                                              const float* __restrict__ St,
                                              float* __restrict__ out) {
  __shared__ float red[256];
  const int b = threadIdx.x;
  float m1 = -1e30f, m2 = -1e30f;
  for (int j = 0; j < 256; ++j) {
    m1 = fmaxf(m1, St[j * 256 + b]);  // row b of S
    m2 = fmaxf(m2, S [j * 256 + b]);  // col b of S
  }
  float s1 = 0.f, s2 = 0.f;
  for (int j = 0; j < 256; ++j) {
    s1 += expf(St[j * 256 + b] - m1);
    s2 += expf(S [j * 256 + b] - m2);
  }
  float v = (m1 + logf(s1)) + (m2 + logf(s2)) - 2.0f * S[(size_t)b * 256 + b];
  red[b] = v;
  __syncthreads();
  for (int st = 128; st > 0; st >>= 1) {
    if (b < st) red[b] += red[b + st];
    __syncthreads();
  }
  if (b == 0) out[0] = red[0] * (1.0f / 512.0f);
}

extern "C" void kernel_launch(void* const* d_in, const int* in_sizes, int n_in,
                              void* d_out, int out_size, void* d_ws, size_t ws_size,
                              hipStream_t stream) {
  const float* concept = (const float*)d_in[0];
  const float* text    = (const float*)d_in[1];
  const int*   tmask   = (const int*)d_in[2];
  const float* Wc      = (const float*)d_in[3];
  const float* bc      = (const float*)d_in[4];
  const float* Ww      = (const float*)d_in[5];
  const float* bw      = (const float*)d_in[6];
  const float* temp    = (const float*)d_in[7];
  float* out = (float*)d_out;
  char* ws = (char*)d_ws;

  // workspace layout (bytes), ~39.1 MB
  float*              Sm   = (float*)(ws + 0);             // 256x256 f32
  float*              Stm  = (float*)(ws + 262144);        // 256x256 f32
  unsigned short*     Xcb  = (unsigned short*)(ws + 524288);    // 8192x768 bf16
  unsigned short*     Xtb  = (unsigned short*)(ws + 13107200);  // 10240x768 bf16
  unsigned short*     Wctb = (unsigned short*)(ws + 28835840);  // 256x768 bf16
  unsigned short*     Wwtb = (unsigned short*)(ws + 29229056);  // 256x768 bf16
  unsigned short*     CFb  = (unsigned short*)(ws + 29622272);  // 8192x256 bf16
  unsigned short*     WFb  = (unsigned short*)(ws + 33816576);  // 10240x256 bf16
  unsigned long long* MBp  = (unsigned long long*)(ws + 39059456);
  float*              NWp  = (float*)(ws + 39061504);

  k_mask<<<1, 256, 0, stream>>>(tmask, MBp, NWp);
  k_cvt<<<6912, 256, 0, stream>>>(concept, text, Xcb, Xtb);
  k_trw<<<1536, 256, 0, stream>>>(Wc, Ww, Wctb, Wwtb);
  k_proj<<<256, 256, 0, stream>>>(Xcb, Wctb, bc, CFb);
  k_proj<<<320, 256, 0, stream>>>(Xtb, Wwtb, bw, WFb);
  dim3 pg(64, 16);
  k_pair<<<pg, 256, 0, stream>>>(CFb, WFb, MBp, NWp, temp, Sm, Stm);
  k_loss<<<1, 256, 0, stream>>>(Sm, Stm, out);
}

// Round 3
// 212.967 us; speedup vs baseline: 1.4496x; 1.0297x over previous
//
#include <hip/hip_runtime.h>
#include <hip/hip_bf16.h>
#include <stdint.h>

// ALBEF contrastive loss: B=256, Q=32, L=40, VW=TW=768, D=256.
// S = sim_i2t/temp; sim_t2i = S^T, so loss = row-LSE + col-LSE of one S.

using f32x4  = __attribute__((ext_vector_type(4))) float;
using bf16x8 = __attribute__((ext_vector_type(8))) short;

__device__ __forceinline__ short f2bf(float f) {
  union { float f; uint32_t u; } x; x.f = f;
  uint32_t r = x.u + 0x7FFFu + ((x.u >> 16) & 1u);  // RNE
  return (short)(r >> 16);
}

// pack 8 f32 -> 8 bf16 via v_cvt_pk_bf16_f32 (RNE, 2 elems/instr)
__device__ __forceinline__ bf16x8 pack8pk(float4 v0, float4 v1) {
  union { uint32_t u[4]; bf16x8 v; } r;
  asm("v_cvt_pk_bf16_f32 %0, %1, %2" : "=v"(r.u[0]) : "v"(v0.x), "v"(v0.y));
  asm("v_cvt_pk_bf16_f32 %0, %1, %2" : "=v"(r.u[1]) : "v"(v0.z), "v"(v0.w));
  asm("v_cvt_pk_bf16_f32 %0, %1, %2" : "=v"(r.u[2]) : "v"(v1.x), "v"(v1.y));
  asm("v_cvt_pk_bf16_f32 %0, %1, %2" : "=v"(r.u[3]) : "v"(v1.z), "v"(v1.w));
  return r.v;
}

// async global->LDS, 16B per lane; LDS dest = wave-uniform base + lane*16
__device__ __forceinline__ void gl_lds16(const unsigned short* g, unsigned short* l) {
  __builtin_amdgcn_global_load_lds(
      (const __attribute__((address_space(1))) void*)g,
      (__attribute__((address_space(3))) void*)l, 16, 0, 0);
}

// ------------- W transpose+cvt (all blocks) + mask preprocess (block 0) ----
__global__ __launch_bounds__(256) void k_trw(const float* __restrict__ Wc,
                                             const float* __restrict__ Ww,
                                             const int* __restrict__ tm,
                                             unsigned short* __restrict__ Wct,
                                             unsigned short* __restrict__ Wwt,
                                             unsigned long long* __restrict__ mb,
                                             float* __restrict__ nw) {
  if (blockIdx.x == 0) {
    int b = threadIdx.x;  // 256 threads, one per batch row
    unsigned long long bits = 0ull;
    int sep = -1;
    #pragma unroll
    for (int t = 1; t < 40; ++t) {
      if (tm[b * 40 + t] > 0) { bits |= (1ull << t); sep = t; }
    }
    if (sep >= 0) bits &= ~(1ull << sep);
    mb[b] = bits;
    nw[b] = (float)__popcll(bits);
  }
  int base = (blockIdx.x * 256 + threadIdx.x) * 4;
  const int N = 196608;  // 768*256
  #pragma unroll
  for (int e = 0; e < 4; ++e) {
    int i = base + e;
    const float* W = (i < N) ? Wc : Ww;
    unsigned short* O = (i < N) ? Wct : Wwt;
    int j = (i < N) ? i : i - N;
    int dd = j / 768, k = j - dd * 768;
    O[j] = (unsigned short)f2bf(W[k * 256 + dd]);
  }
}

// ---------- proj GEMM (f32 X, in-flight cvt) + fused bias + l2norm ---------
// P[M,256] = X[M,768] @ W; per block: 32 rows, 4 waves x 64 cols.
__global__ __launch_bounds__(256) void k_proj(const float* __restrict__ X,
                                              const unsigned short* __restrict__ Wtb,
                                              const float* __restrict__ bias,
                                              unsigned short* __restrict__ out) {
  __shared__ float red[32][4];
  const int m0 = blockIdx.x * 32;
  const int w = threadIdx.x >> 6, l = threadIdx.x & 63;
  const int lr = l & 15, lg = l >> 4;
  const int n0 = w * 64;

  f32x4 acc[2][4];
  #pragma unroll
  for (int mi = 0; mi < 2; ++mi)
    #pragma unroll
    for (int ni = 0; ni < 4; ++ni) acc[mi][ni] = f32x4{0.f, 0.f, 0.f, 0.f};

  const float* p0 = X + (size_t)(m0 + lr) * 768 + lg * 8;
  const float* p1 = p0 + (size_t)16 * 768;

  #pragma unroll 2
  for (int ks = 0; ks < 24; ++ks) {
    const int k0 = ks * 32;
    bf16x8 a0 = pack8pk(*(const float4*)(p0 + k0), *(const float4*)(p0 + k0 + 4));
    bf16x8 a1 = pack8pk(*(const float4*)(p1 + k0), *(const float4*)(p1 + k0 + 4));
    bf16x8 bb[4];
    #pragma unroll
    for (int ni = 0; ni < 4; ++ni)
      bb[ni] = *(const bf16x8*)(Wtb + (size_t)(n0 + ni * 16 + lr) * 768 + k0 + lg * 8);
    #pragma unroll
    for (int ni = 0; ni < 4; ++ni)
      acc[0][ni] = __builtin_amdgcn_mfma_f32_16x16x32_bf16(a0, bb[ni], acc[0][ni], 0, 0, 0);
    #pragma unroll
    for (int ni = 0; ni < 4; ++ni)
      acc[1][ni] = __builtin_amdgcn_mfma_f32_16x16x32_bf16(a1, bb[ni], acc[1][ni], 0, 0, 0);
  }

  float bv[4];
  #pragma unroll
  for (int ni = 0; ni < 4; ++ni) bv[ni] = bias[n0 + ni * 16 + lr];

  float ss[2][4];
  #pragma unroll
  for (int mi = 0; mi < 2; ++mi)
    #pragma unroll
    for (int j = 0; j < 4; ++j) {
      float t = 0.f;
      #pragma unroll
      for (int ni = 0; ni < 4; ++ni) {
        acc[mi][ni][j] += bv[ni];
        t += acc[mi][ni][j] * acc[mi][ni][j];
      }
      ss[mi][j] = t;
    }
  #pragma unroll
  for (int m = 1; m <= 8; m <<= 1)
    #pragma unroll
    for (int mi = 0; mi < 2; ++mi)
      #pragma unroll
      for (int j = 0; j < 4; ++j)
        ss[mi][j] += __shfl_xor(ss[mi][j], m);
  if (lr == 0) {
    #pragma unroll
    for (int mi = 0; mi < 2; ++mi)
      #pragma unroll
      for (int j = 0; j < 4; ++j)
        red[mi * 16 + lg * 4 + j][w] = ss[mi][j];
  }
  __syncthreads();
  #pragma unroll
  for (int mi = 0; mi < 2; ++mi)
    #pragma unroll
    for (int j = 0; j < 4; ++j) {
      int r = mi * 16 + lg * 4 + j;
      float sc = rsqrtf(red[r][0] + red[r][1] + red[r][2] + red[r][3]);
      #pragma unroll
      for (int ni = 0; ni < 4; ++ni)
        out[(size_t)(m0 + r) * 256 + n0 + ni * 16 + lr] =
            (unsigned short)f2bf(acc[mi][ni][j] * sc);
    }
}

// ------------- pairwise sim: 8 b x 16 c per block, 2 b's per wave ----------
// LDS per buffer: [40][256] bf16 = 20KB, physical slot = s ^ (t&7) (16B units)
__global__ __launch_bounds__(256, 2) void k_pair(const unsigned short* __restrict__ CF,
                                                 const unsigned short* __restrict__ WF,
                                                 const unsigned long long* __restrict__ MB,
                                                 const float* __restrict__ NW,
                                                 const float* __restrict__ TEMP,
                                                 float* __restrict__ S,
                                                 float* __restrict__ St) {
  __shared__ unsigned short wfs[2][10240];
  const int tid = threadIdx.x;
  const int w = tid >> 6, l = tid & 63;
  const int lr = l & 15, lg = l >> 4;
  const int b0 = blockIdx.x * 8, c0 = blockIdx.y * 16;
  const float invt = 1.0f / TEMP[0];

  // stage c0 into buf 0: 1280 16B chunks; wave w covers chunks [(w*5+j)*64 ..)
  #pragma unroll
  for (int j = 0; j < 5; ++j) {
    int idx = w * 5 + j;
    int ch = idx * 64 + l;
    int t = ch >> 5, sl = ch & 31;
    gl_lds16(WF + ((size_t)c0 * 40 + t) * 256 + ((sl ^ (t & 7)) * 8),
             &wfs[0][idx * 512]);
  }

  // hoist A frags for this wave's two b's (L2-resident CF): 128 VGPRs
  bf16x8 a[2][2][8];
  #pragma unroll
  for (int bi = 0; bi < 2; ++bi) {
    const int b = b0 + w * 2 + bi;
    #pragma unroll
    for (int mi = 0; mi < 2; ++mi)
      #pragma unroll
      for (int ks = 0; ks < 8; ++ks)
        a[bi][mi][ks] = *(const bf16x8*)(CF + (size_t)(b * 32 + mi * 16 + lr) * 256 + (ks * 4 + lg) * 8);
  }

  asm volatile("s_waitcnt vmcnt(0)" ::: "memory");
  __syncthreads();

  int cur = 0;
  #pragma unroll 1
  for (int ci = 0; ci < 16; ++ci) {
    const int cg = c0 + ci;
    if (ci < 15) {  // prefetch next wf tile into the free buffer
      #pragma unroll
      for (int j = 0; j < 5; ++j) {
        int idx = w * 5 + j;
        int ch = idx * 64 + l;
        int t = ch >> 5, sl = ch & 31;
        gl_lds16(WF + ((size_t)(cg + 1) * 40 + t) * 256 + ((sl ^ (t & 7)) * 8),
                 &wfs[cur ^ 1][idx * 512]);
      }
    }

    f32x4 acc[2][2][3];
    #pragma unroll
    for (int bi = 0; bi < 2; ++bi)
      #pragma unroll
      for (int mi = 0; mi < 2; ++mi)
        #pragma unroll
        for (int ni = 0; ni < 3; ++ni) acc[bi][mi][ni] = f32x4{0.f, 0.f, 0.f, 0.f};

    #pragma unroll
    for (int ks = 0; ks < 8; ++ks) {
      bf16x8 bfv[3];
      #pragma unroll
      for (int ni = 0; ni < 3; ++ni) {
        int t = ni * 16 + lr;
        if (t > 39) t = 39;
        int s = ks * 4 + lg;
        bfv[ni] = *(const bf16x8*)(&wfs[cur][t * 256 + ((s ^ (t & 7)) * 8)]);
      }
      #pragma unroll
      for (int bi = 0; bi < 2; ++bi)
        #pragma unroll
        for (int mi = 0; mi < 2; ++mi)
          #pragma unroll
          for (int ni = 0; ni < 3; ++ni)
            acc[bi][mi][ni] = __builtin_amdgcn_mfma_f32_16x16x32_bf16(a[bi][mi][ks], bfv[ni], acc[bi][mi][ni], 0, 0, 0);
    }

    const unsigned long long vb = MB[cg];
    const float nw = NW[cg];

    #pragma unroll
    for (int bi = 0; bi < 2; ++bi) {
      const int b = b0 + w * 2 + bi;
      // masking: invalid t -> -2 (reference fill)
      bool val[3];
      #pragma unroll
      for (int ni = 0; ni < 3; ++ni) {
        int t = ni * 16 + lr;
        val[ni] = (t < 40) && ((vb >> t) & 1ull);
        if (!val[ni]) {
          #pragma unroll
          for (int mi = 0; mi < 2; ++mi)
            #pragma unroll
            for (int j = 0; j < 4; ++j) acc[bi][mi][ni][j] = -2.0f;
        }
      }

      // per-q max over t -> mean over 32 q
      float rp[2][4];
      #pragma unroll
      for (int mi = 0; mi < 2; ++mi)
        #pragma unroll
        for (int j = 0; j < 4; ++j)
          rp[mi][j] = fmaxf(fmaxf(acc[bi][mi][0][j], acc[bi][mi][1][j]), acc[bi][mi][2][j]);
      #pragma unroll
      for (int m = 1; m < 16; m <<= 1) {
        #pragma unroll
        for (int mi = 0; mi < 2; ++mi)
          #pragma unroll
          for (int j = 0; j < 4; ++j)
            rp[mi][j] = fmaxf(rp[mi][j], __shfl_xor(rp[mi][j], m));
      }
      float rsum = rp[0][0] + rp[0][1] + rp[0][2] + rp[0][3]
                 + rp[1][0] + rp[1][1] + rp[1][2] + rp[1][3];
      rsum += __shfl_xor(rsum, 16);
      rsum += __shfl_xor(rsum, 32);

      // per-t max over q (valid t only) -> mean over n_words
      float cp[3];
      #pragma unroll
      for (int ni = 0; ni < 3; ++ni) {
        cp[ni] = fmaxf(fmaxf(fmaxf(acc[bi][0][ni][0], acc[bi][0][ni][1]),
                             fmaxf(acc[bi][0][ni][2], acc[bi][0][ni][3])),
                       fmaxf(fmaxf(acc[bi][1][ni][0], acc[bi][1][ni][1]),
                             fmaxf(acc[bi][1][ni][2], acc[bi][1][ni][3])));
        cp[ni] = fmaxf(cp[ni], __shfl_xor(cp[ni], 16));
        cp[ni] = fmaxf(cp[ni], __shfl_xor(cp[ni], 32));
      }
      float csum = (val[0] ? cp[0] : 0.f) + (val[1] ? cp[1] : 0.f) + (val[2] ? cp[2] : 0.f);
      #pragma unroll
      for (int m = 1; m < 64; m <<= 1) csum += __shfl_xor(csum, m);
      csum *= 0.25f;  // col values replicated across 4 lane-groups

      float sv = (rsum * 0.03125f + csum / nw) * invt;
      if (l == 0) {
        S [(size_t)b  * 256 + cg] = sv;
        St[(size_t)cg * 256 + b ] = sv;
      }
    }

    asm volatile("s_waitcnt vmcnt(0)" ::: "memory");
    __syncthreads();
    cur ^= 1;
  }
}

// ---------------- loss: row-LSE (via St) + col-LSE of S --------------------
__global__ __launch_bounds__(256) void k_loss(const float* __restrict__ S,
                                              const float* __restrict__ St,
                                              float* __restrict__ out) {
  __shared__ float red[256];
  const int b = threadIdx.x;
  float m1 = -1e30f, m2 = -1e30f;
  for (int j = 0; j < 256; ++j) {
    m1 = fmaxf(m1, St[j * 256 + b]);  // row b of S
    m2 = fmaxf(m2, S [j * 256 + b]);  // col b of S
  }
  float s1 = 0.f, s2 = 0.f;
  for (int j = 0; j < 256; ++j) {
    s1 += expf(St[j * 256 + b] - m1);
    s2 += expf(S [j * 256 + b] - m2);
  }
  float v = (m1 + logf(s1)) + (m2 + logf(s2)) - 2.0f * S[(size_t)b * 256 + b];
  red[b] = v;
  __syncthreads();
  for (int st = 128; st > 0; st >>= 1) {
    if (b < st) red[b] += red[b + st];
    __syncthreads();
  }
  if (b == 0) out[0] = red[0] * (1.0f / 512.0f);
}

extern "C" void kernel_launch(void* const* d_in, const int* in_sizes, int n_in,
                              void* d_out, int out_size, void* d_ws, size_t ws_size,
                              hipStream_t stream) {
  const float* concept = (const float*)d_in[0];
  const float* text    = (const float*)d_in[1];
  const int*   tmask   = (const int*)d_in[2];
  const float* Wc      = (const float*)d_in[3];
  const float* bc      = (const float*)d_in[4];
  const float* Ww      = (const float*)d_in[5];
  const float* bw      = (const float*)d_in[6];
  const float* temp    = (const float*)d_in[7];
  float* out = (float*)d_out;
  char* ws = (char*)d_ws;

  // workspace layout (bytes), ~10.8 MB
  float*              Sm   = (float*)(ws + 0);                  // 256x256 f32
  float*              Stm  = (float*)(ws + 262144);             // 256x256 f32
  unsigned short*     Wctb = (unsigned short*)(ws + 524288);    // 256x768 bf16
  unsigned short*     Wwtb = (unsigned short*)(ws + 917504);    // 256x768 bf16
  unsigned short*     CFb  = (unsigned short*)(ws + 1310720);   // 8192x256 bf16
  unsigned short*     WFb  = (unsigned short*)(ws + 5505024);   // 10240x256 bf16
  unsigned long long* MBp  = (unsigned long long*)(ws + 10747904);
  float*              NWp  = (float*)(ws + 10749952);

  k_trw<<<384, 256, 0, stream>>>(Wc, Ww, tmask, Wctb, Wwtb, MBp, NWp);
  k_proj<<<256, 256, 0, stream>>>(concept, Wctb, bc, CFb);
  k_proj<<<320, 256, 0, stream>>>(text, Wwtb, bw, WFb);
  dim3 pg(32, 16);
  k_pair<<<pg, 256, 0, stream>>>(CFb, WFb, MBp, NWp, temp, Sm, Stm);
  k_loss<<<1, 256, 0, stream>>>(Sm, Stm, out);
}

// Round 4
// 148.011 us; speedup vs baseline: 2.0858x; 1.4389x over previous
//
#include <hip/hip_runtime.h>
#include <hip/hip_bf16.h>
#include <stdint.h>

// ALBEF contrastive loss: B=256, Q=32, L=40, VW=TW=768, D=256.
// S = sim_i2t/temp; sim_t2i = S^T, so loss = row-LSE + col-LSE of one S.

using f32x4  = __attribute__((ext_vector_type(4))) float;
using bf16x8 = __attribute__((ext_vector_type(8))) short;

__device__ __forceinline__ short f2bf(float f) {
  union { float f; uint32_t u; } x; x.f = f;
  uint32_t r = x.u + 0x7FFFu + ((x.u >> 16) & 1u);  // RNE
  return (short)(r >> 16);
}

// pack 8 f32 -> 8 bf16 via v_cvt_pk_bf16_f32 (RNE, 2 elems/instr)
__device__ __forceinline__ bf16x8 pack8pk(float4 v0, float4 v1) {
  union { uint32_t u[4]; bf16x8 v; } r;
  asm("v_cvt_pk_bf16_f32 %0, %1, %2" : "=v"(r.u[0]) : "v"(v0.x), "v"(v0.y));
  asm("v_cvt_pk_bf16_f32 %0, %1, %2" : "=v"(r.u[1]) : "v"(v0.z), "v"(v0.w));
  asm("v_cvt_pk_bf16_f32 %0, %1, %2" : "=v"(r.u[2]) : "v"(v1.x), "v"(v1.y));
  asm("v_cvt_pk_bf16_f32 %0, %1, %2" : "=v"(r.u[3]) : "v"(v1.z), "v"(v1.w));
  return r.v;
}

// async global->LDS, 16B per lane; LDS dest = wave-uniform base + lane*16
__device__ __forceinline__ void gl_lds16(const unsigned short* g, unsigned short* l) {
  __builtin_amdgcn_global_load_lds(
      (const __attribute__((address_space(1))) void*)g,
      (__attribute__((address_space(3))) void*)l, 16, 0, 0);
}

// ---- DPP lane reductions (VALU pipe, not LDS) ----
// 0xB1 = quad_perm(1,0,3,2)=xor1; 0x4E = quad_perm(2,3,0,1)=xor2;
// 0x141 = row_half_mirror; 0x140 = row_mirror.
template <int CTRL>
__device__ __forceinline__ float dppf(float x) {
  return __int_as_float(__builtin_amdgcn_update_dpp(
      0, __float_as_int(x), CTRL, 0xF, 0xF, true));
}
__device__ __forceinline__ float max16(float x) {  // max over 16-lane row
  x = fmaxf(x, dppf<0xB1>(x));
  x = fmaxf(x, dppf<0x4E>(x));
  x = fmaxf(x, dppf<0x141>(x));
  x = fmaxf(x, dppf<0x140>(x));
  return x;
}
__device__ __forceinline__ float sum16(float x) {  // sum over 16-lane row
  x += dppf<0xB1>(x);
  x += dppf<0x4E>(x);
  x += dppf<0x141>(x);
  x += dppf<0x140>(x);
  return x;
}

// ------------- W transpose+cvt (all blocks) + mask preprocess (block 0) ----
__global__ __launch_bounds__(256) void k_trw(const float* __restrict__ Wc,
                                             const float* __restrict__ Ww,
                                             const int* __restrict__ tm,
                                             unsigned short* __restrict__ Wct,
                                             unsigned short* __restrict__ Wwt,
                                             unsigned long long* __restrict__ mb,
                                             float* __restrict__ nw) {
  if (blockIdx.x == 0) {
    int b = threadIdx.x;  // 256 threads, one per batch row
    unsigned long long bits = 0ull;
    int sep = -1;
    #pragma unroll
    for (int t = 1; t < 40; ++t) {
      if (tm[b * 40 + t] > 0) { bits |= (1ull << t); sep = t; }
    }
    if (sep >= 0) bits &= ~(1ull << sep);
    mb[b] = bits;
    nw[b] = (float)__popcll(bits);
  }
  int base = (blockIdx.x * 256 + threadIdx.x) * 4;
  const int N = 196608;  // 768*256
  #pragma unroll
  for (int e = 0; e < 4; ++e) {
    int i = base + e;
    const float* W = (i < N) ? Wc : Ww;
    unsigned short* O = (i < N) ? Wct : Wwt;
    int j = (i < N) ? i : i - N;
    int dd = j / 768, k = j - dd * 768;
    O[j] = (unsigned short)f2bf(W[k * 256 + dd]);
  }
}

// ---------- merged proj GEMM (f32 X, in-flight cvt) + bias + l2norm --------
// blocks 0..255: concept (8192 rows); 256..575: text (10240 rows). BM=32.
__global__ __launch_bounds__(256) void k_proj(const float* __restrict__ Xc,
                                              const float* __restrict__ Xt,
                                              const unsigned short* __restrict__ Wct,
                                              const unsigned short* __restrict__ Wwt,
                                              const float* __restrict__ bc,
                                              const float* __restrict__ bw,
                                              unsigned short* __restrict__ CFb,
                                              unsigned short* __restrict__ WFb) {
  __shared__ float red[32][4];
  const int blk = blockIdx.x;
  const float* X; const unsigned short* Wtb; const float* bias;
  unsigned short* out; int m0;
  if (blk < 256) { X = Xc; Wtb = Wct; bias = bc; out = CFb; m0 = blk * 32; }
  else           { X = Xt; Wtb = Wwt; bias = bw; out = WFb; m0 = (blk - 256) * 32; }

  const int w = threadIdx.x >> 6, l = threadIdx.x & 63;
  const int lr = l & 15, lg = l >> 4;
  const int n0 = w * 64;

  f32x4 acc[2][4];
  #pragma unroll
  for (int mi = 0; mi < 2; ++mi)
    #pragma unroll
    for (int ni = 0; ni < 4; ++ni) acc[mi][ni] = f32x4{0.f, 0.f, 0.f, 0.f};

  const float* p0 = X + (size_t)(m0 + lr) * 768 + lg * 8;
  const float* p1 = p0 + (size_t)16 * 768;

  #pragma unroll 4
  for (int ks = 0; ks < 24; ++ks) {
    const int k0 = ks * 32;
    bf16x8 a0 = pack8pk(*(const float4*)(p0 + k0), *(const float4*)(p0 + k0 + 4));
    bf16x8 a1 = pack8pk(*(const float4*)(p1 + k0), *(const float4*)(p1 + k0 + 4));
    bf16x8 bb[4];
    #pragma unroll
    for (int ni = 0; ni < 4; ++ni)
      bb[ni] = *(const bf16x8*)(Wtb + (size_t)(n0 + ni * 16 + lr) * 768 + k0 + lg * 8);
    #pragma unroll
    for (int ni = 0; ni < 4; ++ni)
      acc[0][ni] = __builtin_amdgcn_mfma_f32_16x16x32_bf16(a0, bb[ni], acc[0][ni], 0, 0, 0);
    #pragma unroll
    for (int ni = 0; ni < 4; ++ni)
      acc[1][ni] = __builtin_amdgcn_mfma_f32_16x16x32_bf16(a1, bb[ni], acc[1][ni], 0, 0, 0);
  }

  float bv[4];
  #pragma unroll
  for (int ni = 0; ni < 4; ++ni) bv[ni] = bias[n0 + ni * 16 + lr];

  float ss[2][4];
  #pragma unroll
  for (int mi = 0; mi < 2; ++mi)
    #pragma unroll
    for (int j = 0; j < 4; ++j) {
      float t = 0.f;
      #pragma unroll
      for (int ni = 0; ni < 4; ++ni) {
        acc[mi][ni][j] += bv[ni];
        t += acc[mi][ni][j] * acc[mi][ni][j];
      }
      ss[mi][j] = t;
    }
  #pragma unroll
  for (int m = 1; m <= 8; m <<= 1)
    #pragma unroll
    for (int mi = 0; mi < 2; ++mi)
      #pragma unroll
      for (int j = 0; j < 4; ++j)
        ss[mi][j] += __shfl_xor(ss[mi][j], m);
  if (lr == 0) {
    #pragma unroll
    for (int mi = 0; mi < 2; ++mi)
      #pragma unroll
      for (int j = 0; j < 4; ++j)
        red[mi * 16 + lg * 4 + j][w] = ss[mi][j];
  }
  __syncthreads();
  #pragma unroll
  for (int mi = 0; mi < 2; ++mi)
    #pragma unroll
    for (int j = 0; j < 4; ++j) {
      int r = mi * 16 + lg * 4 + j;
      float sc = rsqrtf(red[r][0] + red[r][1] + red[r][2] + red[r][3]);
      #pragma unroll
      for (int ni = 0; ni < 4; ++ni)
        out[(size_t)(m0 + r) * 256 + n0 + ni * 16 + lr] =
            (unsigned short)f2bf(acc[mi][ni][j] * sc);
    }
}

// ------------- pairwise sim: 8 b x 16 c per block, 2 b's per wave ----------
// LDS per buffer: [40][256] bf16 = 20KB, physical slot = s ^ (t&7) (16B units)
__global__ __launch_bounds__(256, 2) void k_pair(const unsigned short* __restrict__ CF,
                                                 const unsigned short* __restrict__ WF,
                                                 const unsigned long long* __restrict__ MB,
                                                 const float* __restrict__ NW,
                                                 const float* __restrict__ TEMP,
                                                 float* __restrict__ S,
                                                 float* __restrict__ St) {
  __shared__ unsigned short wfs[2][10240];
  const int tid = threadIdx.x;
  const int w = tid >> 6, l = tid & 63;
  const int lr = l & 15, lg = l >> 4;
  const int b0 = blockIdx.x * 8, c0 = blockIdx.y * 16;
  const float invt = 1.0f / TEMP[0];

  // stage c0 into buf 0: 1280 16B chunks; wave w covers chunks [(w*5+j)*64 ..)
  #pragma unroll
  for (int j = 0; j < 5; ++j) {
    int idx = w * 5 + j;
    int ch = idx * 64 + l;
    int t = ch >> 5, sl = ch & 31;
    gl_lds16(WF + ((size_t)c0 * 40 + t) * 256 + ((sl ^ (t & 7)) * 8),
             &wfs[0][idx * 512]);
  }

  // hoist A frags for this wave's two b's (L2-resident CF)
  bf16x8 a[2][2][8];
  #pragma unroll
  for (int bi = 0; bi < 2; ++bi) {
    const int b = b0 + w * 2 + bi;
    #pragma unroll
    for (int mi = 0; mi < 2; ++mi)
      #pragma unroll
      for (int ks = 0; ks < 8; ++ks)
        a[bi][mi][ks] = *(const bf16x8*)(CF + (size_t)(b * 32 + mi * 16 + lr) * 256 + (ks * 4 + lg) * 8);
  }

  asm volatile("s_waitcnt vmcnt(0)" ::: "memory");
  __builtin_amdgcn_s_barrier();

  int cur = 0;
  #pragma unroll 1
  for (int ci = 0; ci < 16; ++ci) {
    const int cg = c0 + ci;
    if (ci < 15) {  // prefetch next wf tile into the free buffer
      #pragma unroll
      for (int j = 0; j < 5; ++j) {
        int idx = w * 5 + j;
        int ch = idx * 64 + l;
        int t = ch >> 5, sl = ch & 31;
        gl_lds16(WF + ((size_t)(cg + 1) * 40 + t) * 256 + ((sl ^ (t & 7)) * 8),
                 &wfs[cur ^ 1][idx * 512]);
      }
    }
    __builtin_amdgcn_sched_barrier(0);  // pin stage issue before everything below

    f32x4 acc[2][2][3];
    #pragma unroll
    for (int bi = 0; bi < 2; ++bi)
      #pragma unroll
      for (int mi = 0; mi < 2; ++mi)
        #pragma unroll
        for (int ni = 0; ni < 3; ++ni) acc[bi][mi][ni] = f32x4{0.f, 0.f, 0.f, 0.f};

    __builtin_amdgcn_s_setprio(1);
    #pragma unroll
    for (int ks = 0; ks < 8; ++ks) {
      bf16x8 bfv[3];
      #pragma unroll
      for (int ni = 0; ni < 3; ++ni) {
        int t = ni * 16 + lr;
        if (t > 39) t = 39;
        int s = ks * 4 + lg;
        bfv[ni] = *(const bf16x8*)(&wfs[cur][t * 256 + ((s ^ (t & 7)) * 8)]);
      }
      #pragma unroll
      for (int bi = 0; bi < 2; ++bi)
        #pragma unroll
        for (int mi = 0; mi < 2; ++mi)
          #pragma unroll
          for (int ni = 0; ni < 3; ++ni)
            acc[bi][mi][ni] = __builtin_amdgcn_mfma_f32_16x16x32_bf16(a[bi][mi][ks], bfv[ni], acc[bi][mi][ni], 0, 0, 0);
    }
    __builtin_amdgcn_s_setprio(0);

    const unsigned long long vb = MB[cg];
    const float nw = NW[cg];
    bool val[3];
    #pragma unroll
    for (int ni = 0; ni < 3; ++ni) {
      int t = ni * 16 + lr;
      val[ni] = (t < 40) && ((vb >> t) & 1ull);
    }

    #pragma unroll
    for (int bi = 0; bi < 2; ++bi) {
      const int b = b0 + w * 2 + bi;

      // row-part: per-q max over t (invalid t -> -2), then mean over 32 q
      float rp[2][4];
      #pragma unroll
      for (int mi = 0; mi < 2; ++mi)
        #pragma unroll
        for (int j = 0; j < 4; ++j) {
          float v0 = val[0] ? acc[bi][mi][0][j] : -2.0f;
          float v1 = val[1] ? acc[bi][mi][1][j] : -2.0f;
          float v2 = val[2] ? acc[bi][mi][2][j] : -2.0f;
          rp[mi][j] = max16(fmaxf(fmaxf(v0, v1), v2));  // uniform over lr
        }
      float rsum = rp[0][0] + rp[0][1] + rp[0][2] + rp[0][3]
                 + rp[1][0] + rp[1][1] + rp[1][2] + rp[1][3];
      rsum += __shfl_xor(rsum, 16);   // sum the 4 lg groups
      rsum += __shfl_xor(rsum, 32);

      // col-part: per-t max over 32 q, mean over valid t
      float cp[3];
      #pragma unroll
      for (int ni = 0; ni < 3; ++ni) {
        float m = fmaxf(fmaxf(fmaxf(acc[bi][0][ni][0], acc[bi][0][ni][1]),
                              fmaxf(acc[bi][0][ni][2], acc[bi][0][ni][3])),
                        fmaxf(fmaxf(acc[bi][1][ni][0], acc[bi][1][ni][1]),
                              fmaxf(acc[bi][1][ni][2], acc[bi][1][ni][3])));
        m = fmaxf(m, __shfl_xor(m, 16));
        m = fmaxf(m, __shfl_xor(m, 32));
        cp[ni] = val[ni] ? m : 0.0f;
      }
      float csum = sum16(cp[0] + cp[1] + cp[2]);  // sum over lr (16 t per ni)

      float sv = (rsum * 0.03125f + csum / nw) * invt;
      if (l == 0) {
        S [(size_t)b  * 256 + cg] = sv;
        St[(size_t)cg * 256 + b ] = sv;
      }
    }

    if (ci < 15) {
      // 4 S/St stores may stay in flight; the 5 stage loads must be done
      asm volatile("s_waitcnt vmcnt(4)" ::: "memory");
      __builtin_amdgcn_s_barrier();
      __builtin_amdgcn_sched_barrier(0);
    }
    cur ^= 1;
  }
}

// ---------------- loss stage 1: per-b row/col LSE of S ----------------------
__global__ __launch_bounds__(256) void k_loss1(const float* __restrict__ S,
                                               const float* __restrict__ St,
                                               float* __restrict__ v) {
  __shared__ float lred[2][4], sred[2][4];
  const int b = blockIdx.x, j = threadIdx.x;
  const int w = j >> 6, l = j & 63;
  float s1v = S [(size_t)b * 256 + j];  // row b of S
  float s2v = St[(size_t)b * 256 + j];  // col b of S
  float m1 = s1v, m2 = s2v;
  #pragma unroll
  for (int m = 1; m < 64; m <<= 1) {
    m1 = fmaxf(m1, __shfl_xor(m1, m));
    m2 = fmaxf(m2, __shfl_xor(m2, m));
  }
  if (l == 0) { lred[0][w] = m1; lred[1][w] = m2; }
  __syncthreads();
  m1 = fmaxf(fmaxf(lred[0][0], lred[0][1]), fmaxf(lred[0][2], lred[0][3]));
  m2 = fmaxf(fmaxf(lred[1][0], lred[1][1]), fmaxf(lred[1][2], lred[1][3]));
  float e1 = expf(s1v - m1), e2 = expf(s2v - m2);
  #pragma unroll
  for (int m = 1; m < 64; m <<= 1) {
    e1 += __shfl_xor(e1, m);
    e2 += __shfl_xor(e2, m);
  }
  if (l == 0) { sred[0][w] = e1; sred[1][w] = e2; }
  __syncthreads();
  if (j == 0) {
    float s1 = sred[0][0] + sred[0][1] + sred[0][2] + sred[0][3];
    float s2 = sred[1][0] + sred[1][1] + sred[1][2] + sred[1][3];
    v[b] = (m1 + logf(s1)) + (m2 + logf(s2)) - 2.0f * S[(size_t)b * 257];
  }
}

// ---------------- loss stage 2: mean ---------------------------------------
__global__ __launch_bounds__(256) void k_loss2(const float* __restrict__ v,
                                               float* __restrict__ out) {
  __shared__ float r[4];
  const int j = threadIdx.x;
  float x = v[j];
  #pragma unroll
  for (int m = 1; m < 64; m <<= 1) x += __shfl_xor(x, m);
  if ((j & 63) == 0) r[j >> 6] = x;
  __syncthreads();
  if (j == 0) out[0] = (r[0] + r[1] + r[2] + r[3]) * (1.0f / 512.0f);
}

extern "C" void kernel_launch(void* const* d_in, const int* in_sizes, int n_in,
                              void* d_out, int out_size, void* d_ws, size_t ws_size,
                              hipStream_t stream) {
  const float* concept = (const float*)d_in[0];
  const float* text    = (const float*)d_in[1];
  const int*   tmask   = (const int*)d_in[2];
  const float* Wc      = (const float*)d_in[3];
  const float* bc      = (const float*)d_in[4];
  const float* Ww      = (const float*)d_in[5];
  const float* bw      = (const float*)d_in[6];
  const float* temp    = (const float*)d_in[7];
  float* out = (float*)d_out;
  char* ws = (char*)d_ws;

  // workspace layout (bytes), ~10.8 MB
  float*              Sm   = (float*)(ws + 0);                  // 256x256 f32
  float*              Stm  = (float*)(ws + 262144);             // 256x256 f32
  unsigned short*     Wctb = (unsigned short*)(ws + 524288);    // 256x768 bf16
  unsigned short*     Wwtb = (unsigned short*)(ws + 917504);    // 256x768 bf16
  unsigned short*     CFb  = (unsigned short*)(ws + 1310720);   // 8192x256 bf16
  unsigned short*     WFb  = (unsigned short*)(ws + 5505024);   // 10240x256 bf16
  unsigned long long* MBp  = (unsigned long long*)(ws + 10747904);
  float*              NWp  = (float*)(ws + 10749952);
  float*              Vb   = (float*)(ws + 10751104);           // 256 f32

  k_trw<<<384, 256, 0, stream>>>(Wc, Ww, tmask, Wctb, Wwtb, MBp, NWp);
  k_proj<<<576, 256, 0, stream>>>(concept, text, Wctb, Wwtb, bc, bw, CFb, WFb);
  dim3 pg(32, 16);
  k_pair<<<pg, 256, 0, stream>>>(CFb, WFb, MBp, NWp, temp, Sm, Stm);
  k_loss1<<<256, 256, 0, stream>>>(Sm, Stm, Vb);
  k_loss2<<<1, 256, 0, stream>>>(Vb, out);
}